// Round 1
// baseline (532.780 us; speedup 1.0000x reference)
//
#include <hip/hip_runtime.h>
#include <hip/hip_bf16.h>
#include <math.h>

#define BB 16
#define SS 2048
#define DD 128
#define BQ 64      // q rows per block
#define BK 64      // keys per tile
#define NW 4       // waves per block
#define KLD 136    // K tile LDS row stride (bf16 elems), 272B rows -> 16B aligned, banks spread
#define VLD 72     // V^T LDS row stride (144B rows, aligned)
#define PLD 72     // P LDS row stride

typedef __attribute__((ext_vector_type(8))) __bf16 bf16x8;
typedef __attribute__((ext_vector_type(4))) float f32x4;

__device__ __forceinline__ float rmax16(float v) {
  v = fmaxf(v, __shfl_xor(v, 1));
  v = fmaxf(v, __shfl_xor(v, 2));
  v = fmaxf(v, __shfl_xor(v, 4));
  v = fmaxf(v, __shfl_xor(v, 8));
  return v;
}
__device__ __forceinline__ float rsum16(float v) {
  v += __shfl_xor(v, 1);
  v += __shfl_xor(v, 2);
  v += __shfl_xor(v, 4);
  v += __shfl_xor(v, 8);
  return v;
}

// stage one BK x DD fp32 tile into LDS as bf16, row-major padded
__device__ __forceinline__ void stage_k(const float* __restrict__ src0,
                                        __bf16* lK, int strow, int stcol) {
  const float* src = src0 + (size_t)strow * DD + stcol;
  __bf16* dst = lK + strow * KLD + stcol;
#pragma unroll
  for (int i = 0; i < 4; ++i) {
    bf16x8 w;
#pragma unroll
    for (int j = 0; j < 8; ++j) w[j] = (__bf16)src[i * 8 + j];
    *(bf16x8*)(dst + i * 8) = w;
  }
}

// QK^T for one BK tile: 16 q rows x 64 keys, contraction over D=128
__device__ __forceinline__ void qk_tile(const bf16x8 aq[4], const __bf16* lK,
                                        int l16, int quad, f32x4 sacc[4]) {
#pragma unroll
  for (int nb = 0; nb < 4; ++nb) {
    f32x4 acc = {0.f, 0.f, 0.f, 0.f};
#pragma unroll
    for (int ks = 0; ks < 4; ++ks) {
      bf16x8 bk = *(const bf16x8*)(lK + (nb * 16 + l16) * KLD + ks * 32 + quad * 8);
      acc = __builtin_amdgcn_mfma_f32_16x16x32_bf16(aq[ks], bk, acc, 0, 0, 0);
    }
    sacc[nb] = acc;
  }
}

__global__ __launch_bounds__(256, 2)
void attn_fused(const float* __restrict__ q, const float* __restrict__ k,
                const float* __restrict__ v, float* __restrict__ ctx,
                float* __restrict__ attn) {
  __shared__ __align__(16) __bf16 lK[BK * KLD];       // 17408 B
  __shared__ __align__(16) __bf16 lV[DD * VLD];       // 18432 B  (V transposed: [d][key])
  __shared__ __align__(16) __bf16 lP[NW * 16 * PLD];  //  9216 B

  const int tid  = threadIdx.x;
  const int wave = tid >> 6;
  const int lane = tid & 63;
  const int quad = lane >> 4;
  const int l16  = lane & 15;

  const int b     = blockIdx.y;
  const int q0    = blockIdx.x * BQ;
  const int wrow0 = q0 + wave * 16;  // first q row of this wave

  const float scale = 0.08838834764831845f;  // 1/sqrt(128)

  // ---- load Q fragments (A-layout: m=lane&15, k=quad*8+j), scale folded ----
  bf16x8 aq[4];
  {
    const float* qrow = q + ((size_t)b * SS + (wrow0 + l16)) * DD;
#pragma unroll
    for (int ks = 0; ks < 4; ++ks) {
      const float* p = qrow + ks * 32 + quad * 8;
      bf16x8 a;
#pragma unroll
      for (int j = 0; j < 8; ++j) a[j] = (__bf16)(p[j] * scale);
      aq[ks] = a;
    }
  }

  float mrow[4], lrow[4];
#pragma unroll
  for (int r = 0; r < 4; ++r) { mrow[r] = -1e30f; lrow[r] = 0.0f; }

  const int strow = tid >> 2;         // K staging: row 0..63
  const int stcol = (tid & 3) * 32;   //            col chunk
  const int vkey  = tid & 63;         // V staging: key 0..63
  const int vcol  = (tid >> 6) * 32;  //            d chunk

  // ================= Phase 1: softmax stats =================
  for (int kt = 0; kt < SS / BK; ++kt) {
    const size_t kk0 = (size_t)kt * BK;
    __syncthreads();
    stage_k(k + ((size_t)b * SS + kk0) * DD, lK, strow, stcol);
    __syncthreads();

    f32x4 sacc[4];
    qk_tile(aq, lK, l16, quad, sacc);

#pragma unroll
    for (int r = 0; r < 4; ++r) {
      float tm = fmaxf(fmaxf(sacc[0][r], sacc[1][r]), fmaxf(sacc[2][r], sacc[3][r]));
      tm = rmax16(tm);
      float mnew = fmaxf(mrow[r], tm);
      float ps = __expf(sacc[0][r] - mnew) + __expf(sacc[1][r] - mnew) +
                 __expf(sacc[2][r] - mnew) + __expf(sacc[3][r] - mnew);
      ps = rsum16(ps);
      lrow[r] = lrow[r] * __expf(mrow[r] - mnew) + ps;
      mrow[r] = mnew;
    }
  }

  float mu[4];
#pragma unroll
  for (int r = 0; r < 4; ++r) mu[r] = mrow[r] + logf(lrow[r]);

  f32x4 cacc[8];
#pragma unroll
  for (int nb = 0; nb < 8; ++nb) cacc[nb] = (f32x4){0.f, 0.f, 0.f, 0.f};

  // ================= Phase 2: attn write + PV =================
  for (int kt = 0; kt < SS / BK; ++kt) {
    const size_t kk0 = (size_t)kt * BK;
    __syncthreads();
    stage_k(k + ((size_t)b * SS + kk0) * DD, lK, strow, stcol);
    {  // stage V transposed: lV[d][key]
      const float* src = v + ((size_t)b * SS + kk0 + vkey) * DD + vcol;
#pragma unroll
      for (int i = 0; i < 32; ++i) {
        lV[(vcol + i) * VLD + vkey] = (__bf16)src[i];
      }
    }
    __syncthreads();

    f32x4 sacc[4];
    qk_tile(aq, lK, l16, quad, sacc);

    // P = exp(s - mu): write fp32 to global attn, bf16 to LDS for PV
#pragma unroll
    for (int nb = 0; nb < 4; ++nb) {
#pragma unroll
      for (int r = 0; r < 4; ++r) {
        float p = __expf(sacc[nb][r] - mu[r]);
        attn[((size_t)b * SS + (wrow0 + quad * 4 + r)) * (size_t)SS + kk0 + nb * 16 + l16] = p;
        lP[(wave * 16 + quad * 4 + r) * PLD + nb * 16 + l16] = (__bf16)p;
      }
    }
    __syncthreads();

    // PV: context += P (A-layout from LDS) * V^T (B-layout from LDS)
#pragma unroll
    for (int kk = 0; kk < 2; ++kk) {
      bf16x8 ap = *(const bf16x8*)(lP + (wave * 16 + l16) * PLD + kk * 32 + quad * 8);
#pragma unroll
      for (int nb = 0; nb < 8; ++nb) {
        bf16x8 bv = *(const bf16x8*)(lV + (nb * 16 + l16) * VLD + kk * 32 + quad * 8);
        cacc[nb] = __builtin_amdgcn_mfma_f32_16x16x32_bf16(ap, bv, cacc[nb], 0, 0, 0);
      }
    }
  }

  // ---- store context ----
#pragma unroll
  for (int nb = 0; nb < 8; ++nb)
#pragma unroll
    for (int r = 0; r < 4; ++r)
      ctx[((size_t)b * SS + (wrow0 + quad * 4 + r)) * DD + nb * 16 + l16] = cacc[nb][r];
}

extern "C" void kernel_launch(void* const* d_in, const int* in_sizes, int n_in,
                              void* d_out, int out_size, void* d_ws, size_t ws_size,
                              hipStream_t stream) {
  const float* q = (const float*)d_in[0];
  const float* k = (const float*)d_in[1];
  const float* v = (const float*)d_in[2];
  float* ctx  = (float*)d_out;
  float* attn = ctx + (size_t)BB * SS * DD;

  dim3 grid(SS / BQ, BB, 1);
  dim3 block(256, 1, 1);
  attn_fused<<<grid, block, 0, stream>>>(q, k, v, ctx, attn);
}

// Round 2
// 442.471 us; speedup vs baseline: 1.2041x; 1.2041x over previous
//
#include <hip/hip_runtime.h>
#include <hip/hip_bf16.h>
#include <math.h>

#define BB 16
#define SS 2048
#define DD 128
#define BQ 64      // q rows per block
#define BK 64      // keys per tile
#define NW 4       // waves per block
#define KLD 136    // K tile LDS row stride (bf16), 272B rows, 16B-aligned
#define VLD 72     // V^T / P LDS row stride (144B rows, 16B-aligned)
#define PLD 72
#define NELEM (BB * SS * DD)   // 4194304 per tensor

typedef __attribute__((ext_vector_type(8))) __bf16 bf16x8;
typedef __attribute__((ext_vector_type(4))) float f32x4;

__device__ __forceinline__ float rmax16(float v) {
  v = fmaxf(v, __shfl_xor(v, 1));
  v = fmaxf(v, __shfl_xor(v, 2));
  v = fmaxf(v, __shfl_xor(v, 4));
  v = fmaxf(v, __shfl_xor(v, 8));
  return v;
}
__device__ __forceinline__ float rsum16(float v) {
  v += __shfl_xor(v, 1);
  v += __shfl_xor(v, 2);
  v += __shfl_xor(v, 4);
  v += __shfl_xor(v, 8);
  return v;
}

// ---------- prep 1: q*scale and k -> bf16 row-major ----------
__global__ __launch_bounds__(256)
void prep_qk(const float* __restrict__ q, const float* __restrict__ k,
             __bf16* __restrict__ qs, __bf16* __restrict__ kb) {
  const int NCH = NELEM / 8;
  int g = blockIdx.x * 256 + threadIdx.x;  // 0 .. 2*NCH-1
  const float* src;
  __bf16* dst;
  float sc;
  if (g < NCH) { src = q; dst = qs; sc = 0.08838834764831845f; }
  else         { g -= NCH; src = k; dst = kb; sc = 1.0f; }
  const float4* p = (const float4*)(src + (size_t)g * 8);
  float4 a = p[0], b = p[1];
  bf16x8 w;
  w[0] = (__bf16)(a.x * sc); w[1] = (__bf16)(a.y * sc);
  w[2] = (__bf16)(a.z * sc); w[3] = (__bf16)(a.w * sc);
  w[4] = (__bf16)(b.x * sc); w[5] = (__bf16)(b.y * sc);
  w[6] = (__bf16)(b.z * sc); w[7] = (__bf16)(b.w * sc);
  ((bf16x8*)dst)[g] = w;
}

// ---------- prep 2: v -> bf16 transposed [b][d][s] ----------
__global__ __launch_bounds__(256)
void prep_vt(const float* __restrict__ v, __bf16* __restrict__ vt) {
  __shared__ __align__(16) __bf16 lT[DD * VLD];
  const int tid = threadIdx.x;
  const int b = blockIdx.y;
  const int s0 = blockIdx.x * 64;

  const int key = tid >> 2;
  const int dc = (tid & 3) * 32;
  const float* src = v + ((size_t)b * SS + s0 + key) * DD + dc;
#pragma unroll
  for (int i = 0; i < 8; ++i) {
    float4 f = ((const float4*)src)[i];
    lT[(dc + i * 4 + 0) * VLD + key] = (__bf16)f.x;
    lT[(dc + i * 4 + 1) * VLD + key] = (__bf16)f.y;
    lT[(dc + i * 4 + 2) * VLD + key] = (__bf16)f.z;
    lT[(dc + i * 4 + 3) * VLD + key] = (__bf16)f.w;
  }
  __syncthreads();
#pragma unroll
  for (int j = 0; j < 4; ++j) {
    int c = tid + j * 256;          // 1024 chunks: 128 d x 8 s-chunks
    int d = c >> 3, sc2 = c & 7;
    bf16x8 w = *(const bf16x8*)(lT + d * VLD + sc2 * 8);
    *(bf16x8*)(vt + ((size_t)b * DD + d) * SS + s0 + sc2 * 8) = w;
  }
}

// ---------- staging helpers (bf16 sources, 16B vector ops) ----------
__device__ __forceinline__ void stage_k(const __bf16* __restrict__ kb,
                                        __bf16* lK, int b, int kk0, int tid) {
#pragma unroll
  for (int j = 0; j < 4; ++j) {
    int c = tid + j * 256;          // 1024 chunks: 64 rows x 16 col-chunks
    int row = c >> 4, cc = c & 15;
    bf16x8 w = *(const bf16x8*)(kb + ((size_t)b * SS + kk0 + row) * DD + cc * 8);
    *(bf16x8*)(lK + row * KLD + cc * 8) = w;
  }
}
__device__ __forceinline__ void stage_v(const __bf16* __restrict__ vt,
                                        __bf16* lV, int b, int kk0, int tid) {
#pragma unroll
  for (int j = 0; j < 4; ++j) {
    int c = tid + j * 256;          // 1024 chunks: 128 d-rows x 8 key-chunks
    int row = c >> 3, sc = c & 7;
    bf16x8 w = *(const bf16x8*)(vt + ((size_t)b * DD + row) * SS + kk0 + sc * 8);
    *(bf16x8*)(lV + row * VLD + sc * 8) = w;
  }
}

__device__ __forceinline__ void qk_tile(const bf16x8 aq[4], const __bf16* lK,
                                        int l16, int quad, f32x4 sacc[4]) {
#pragma unroll
  for (int nb = 0; nb < 4; ++nb) {
    f32x4 acc = {0.f, 0.f, 0.f, 0.f};
#pragma unroll
    for (int ks = 0; ks < 4; ++ks) {
      bf16x8 bk = *(const bf16x8*)(lK + (nb * 16 + l16) * KLD + ks * 32 + quad * 8);
      acc = __builtin_amdgcn_mfma_f32_16x16x32_bf16(aq[ks], bk, acc, 0, 0, 0);
    }
    sacc[nb] = acc;
  }
}

__global__ __launch_bounds__(256, 3)
void attn_fused(const __bf16* __restrict__ qs, const __bf16* __restrict__ kb,
                const __bf16* __restrict__ vt, float* __restrict__ ctx,
                float* __restrict__ attn) {
  __shared__ __align__(16) __bf16 lK[BK * KLD];       // 17408 B
  __shared__ __align__(16) __bf16 lV[DD * VLD];       // 18432 B
  __shared__ __align__(16) __bf16 lP[BQ * PLD];       //  9216 B

  const int tid  = threadIdx.x;
  const int wave = tid >> 6;
  const int lane = tid & 63;
  const int quad = lane >> 4;
  const int l16  = lane & 15;

  const int b     = blockIdx.y;
  const int q0    = blockIdx.x * BQ;
  const int wrow0 = q0 + wave * 16;

  // Q fragments (pre-scaled bf16): A-layout m=l16, k=quad*8+j
  bf16x8 aq[4];
  {
    const __bf16* qrow = qs + ((size_t)b * SS + wrow0 + l16) * DD;
#pragma unroll
    for (int ks = 0; ks < 4; ++ks)
      aq[ks] = *(const bf16x8*)(qrow + ks * 32 + quad * 8);
  }

  float mrow[4], lrow[4];
#pragma unroll
  for (int r = 0; r < 4; ++r) { mrow[r] = -1e30f; lrow[r] = 0.0f; }

  // ================= Phase 1: softmax stats =================
  for (int kt = 0; kt < SS / BK; ++kt) {
    __syncthreads();
    stage_k(kb, lK, b, kt * BK, tid);
    __syncthreads();

    f32x4 sacc[4];
    qk_tile(aq, lK, l16, quad, sacc);

#pragma unroll
    for (int r = 0; r < 4; ++r) {
      float tm = fmaxf(fmaxf(sacc[0][r], sacc[1][r]), fmaxf(sacc[2][r], sacc[3][r]));
      tm = rmax16(tm);
      float mnew = fmaxf(mrow[r], tm);
      float ps = __expf(sacc[0][r] - mnew) + __expf(sacc[1][r] - mnew) +
                 __expf(sacc[2][r] - mnew) + __expf(sacc[3][r] - mnew);
      ps = rsum16(ps);
      lrow[r] = lrow[r] * __expf(mrow[r] - mnew) + ps;
      mrow[r] = mnew;
    }
  }

  float mu[4];
#pragma unroll
  for (int r = 0; r < 4; ++r) mu[r] = mrow[r] + logf(lrow[r]);

  f32x4 cacc[8];
#pragma unroll
  for (int nb = 0; nb < 8; ++nb) cacc[nb] = (f32x4){0.f, 0.f, 0.f, 0.f};

  // ================= Phase 2: attn write + PV =================
  for (int kt = 0; kt < SS / BK; ++kt) {
    const int kk0 = kt * BK;
    __syncthreads();   // protect lK/lV/lP from previous iteration's readers
    stage_k(kb, lK, b, kk0, tid);
    stage_v(vt, lV, b, kk0, tid);
    __syncthreads();

    f32x4 sacc[4];
    qk_tile(aq, lK, l16, quad, sacc);

    // P = exp(s - mu) -> LDS (bf16)
#pragma unroll
    for (int nb = 0; nb < 4; ++nb)
#pragma unroll
      for (int r = 0; r < 4; ++r) {
        float p = __expf(sacc[nb][r] - mu[r]);
        lP[(wave * 16 + quad * 4 + r) * PLD + nb * 16 + l16] = (__bf16)p;
      }
    __syncthreads();

    // PV: ctx += P * V^T
#pragma unroll
    for (int kk = 0; kk < 2; ++kk) {
      bf16x8 ap = *(const bf16x8*)(lP + (wave * 16 + l16) * PLD + kk * 32 + quad * 8);
#pragma unroll
      for (int nb = 0; nb < 8; ++nb) {
        bf16x8 bv = *(const bf16x8*)(lV + (nb * 16 + l16) * VLD + kk * 32 + quad * 8);
        cacc[nb] = __builtin_amdgcn_mfma_f32_16x16x32_bf16(ap, bv, cacc[nb], 0, 0, 0);
      }
    }

    // attn write, coalesced float4 from lP: thread -> (row = tid/4, 16 keys)
    {
      const int row = tid >> 2;
      const int c0 = (tid & 3) * 16;
      bf16x8 w0 = *(const bf16x8*)(lP + row * PLD + c0);
      bf16x8 w1 = *(const bf16x8*)(lP + row * PLD + c0 + 8);
      float* dst = attn + ((size_t)b * SS + q0 + row) * (size_t)SS + kk0 + c0;
      float4 o;
      o.x = (float)w0[0]; o.y = (float)w0[1]; o.z = (float)w0[2]; o.w = (float)w0[3];
      ((float4*)dst)[0] = o;
      o.x = (float)w0[4]; o.y = (float)w0[5]; o.z = (float)w0[6]; o.w = (float)w0[7];
      ((float4*)dst)[1] = o;
      o.x = (float)w1[0]; o.y = (float)w1[1]; o.z = (float)w1[2]; o.w = (float)w1[3];
      ((float4*)dst)[2] = o;
      o.x = (float)w1[4]; o.y = (float)w1[5]; o.z = (float)w1[6]; o.w = (float)w1[7];
      ((float4*)dst)[3] = o;
    }
  }

  // ---- store context ----
#pragma unroll
  for (int nb = 0; nb < 8; ++nb)
#pragma unroll
    for (int r = 0; r < 4; ++r)
      ctx[((size_t)b * SS + wrow0 + quad * 4 + r) * DD + nb * 16 + l16] = cacc[nb][r];
}

extern "C" void kernel_launch(void* const* d_in, const int* in_sizes, int n_in,
                              void* d_out, int out_size, void* d_ws, size_t ws_size,
                              hipStream_t stream) {
  const float* q = (const float*)d_in[0];
  const float* k = (const float*)d_in[1];
  const float* v = (const float*)d_in[2];
  float* ctx  = (float*)d_out;
  float* attn = ctx + (size_t)BB * SS * DD;

  __bf16* qs = (__bf16*)d_ws;
  __bf16* kb = qs + (size_t)NELEM;
  __bf16* vt = kb + (size_t)NELEM;

  prep_qk<<<2 * (NELEM / 8) / 256, 256, 0, stream>>>(q, k, qs, kb);
  prep_vt<<<dim3(SS / 64, BB), 256, 0, stream>>>(v, vt);
  attn_fused<<<dim3(SS / BQ, BB), 256, 0, stream>>>(qs, kb, vt, ctx, attn);
}